// Round 1
// 393.927 us; speedup vs baseline: 1.3167x; 1.3167x over previous
//
#include <hip/hip_runtime.h>
#include <math.h>

#define B_ 16
#define L_ 4096
#define H_ 8
#define E_ 64
#define C_ 512     // H*E
#define K_ 24
#define NT 256
#define RPAD 257   // padded row stride (float2 units) for the 16x256 LDS matrix

__device__ __forceinline__ int br12(int x) { return (int)(__brev((unsigned)x) >> 20); }

__device__ __forceinline__ float2 cmul(float2 a, float2 b) {
    return make_float2(a.x * b.x - a.y * b.y, a.x * b.y + a.y * b.x);
}
__device__ __forceinline__ float2 cadd(float2 a, float2 b) { return make_float2(a.x + b.x, a.y + b.y); }
__device__ __forceinline__ float2 csub(float2 a, float2 b) { return make_float2(a.x - b.x, a.y - b.y); }

// 16-point DIF FFT, natural-order input; output: X[k] = a[br4[k]]
__device__ __forceinline__ void fft16(float2 a[16]) {
    const float r2 = 0.70710678118654752f;
    const float c1 = 0.92387953251128676f;  // cos(pi/8)
    const float s1 = 0.38268343236508977f;  // sin(pi/8)
    const float2 W16[8] = {
        make_float2(1.f, 0.f),  make_float2(c1, -s1),  make_float2(r2, -r2),  make_float2(s1, -c1),
        make_float2(0.f, -1.f), make_float2(-s1, -c1), make_float2(-r2, -r2), make_float2(-c1, -s1)};
    #pragma unroll
    for (int j = 0; j < 8; ++j) {
        float2 u = a[j], v = a[j + 8];
        a[j]     = cadd(u, v);
        a[j + 8] = cmul(csub(u, v), W16[j]);
    }
    #pragma unroll
    for (int b = 0; b < 16; b += 8)
        #pragma unroll
        for (int j = 0; j < 4; ++j) {
            float2 u = a[b + j], v = a[b + j + 4];
            a[b + j]     = cadd(u, v);
            a[b + j + 4] = cmul(csub(u, v), W16[2 * j]);
        }
    #pragma unroll
    for (int b = 0; b < 16; b += 4)
        #pragma unroll
        for (int j = 0; j < 2; ++j) {
            float2 u = a[b + j], v = a[b + j + 2];
            a[b + j]     = cadd(u, v);
            a[b + j + 2] = cmul(csub(u, v), W16[4 * j]);
        }
    #pragma unroll
    for (int b = 0; b < 16; b += 2) {
        float2 u = a[b], v = a[b + 1];
        a[b]     = cadd(u, v);
        a[b + 1] = csub(u, v);
    }
}

// ---------------- zero scratch ----------------
__global__ __launch_bounds__(256) void k_zero(float* __restrict__ p, int n) {
    int i = blockIdx.x * 256 + threadIdx.x;
    if (i < n) p[i] = 0.f;
}

// ---------------- transpose/pack: (b,tau,c) -> z[bl][c][tau] = (q,k) ----------------
__global__ __launch_bounds__(256) void k_transpose(const float* __restrict__ q,
                                                   const float* __restrict__ k,
                                                   float2* __restrict__ z,
                                                   int b0) {
    __shared__ float tq[64][65];
    __shared__ float tk[64][65];
    int bl = blockIdx.z;
    int b  = b0 + bl;
    int t0 = blockIdx.x * 64;
    int c0 = blockIdx.y * 64;
    int tx = threadIdx.x & 63;
    int ty = threadIdx.x >> 6;
    const size_t base = (size_t)b * L_ * C_;
    for (int rr = ty; rr < 64; rr += 4) {
        size_t off = base + (size_t)(t0 + rr) * C_ + (c0 + tx);
        tq[rr][tx] = q[off];
        tk[rr][tx] = k[off];
    }
    __syncthreads();
    for (int rr = ty; rr < 64; rr += 4) {
        size_t off = ((size_t)bl * C_ + (c0 + rr)) * L_ + (t0 + tx);
        z[off] = make_float2(tq[tx][rr], tk[tx][rr]);
    }
}

// ---------------- forward FFT (register radix-16, 3 phases) + cross-spectrum ----------------
__global__ __launch_bounds__(256) void k_fft_accum(const float2* __restrict__ z,
                                                   float* __restrict__ cross, // B*L*2 floats
                                                   int b0) {
    __shared__ float2 s[16 * RPAD];   // 4112 float2 = 32.9 KB
    __shared__ float2 tw256[256];     // tw256[r1*16+m2] = W256^{m2*r1}
    const int br4[16] = {0, 8, 4, 12, 2, 10, 6, 14, 1, 9, 5, 13, 3, 11, 7, 15};
    int t  = threadIdx.x;
    int bl = blockIdx.y;
    int b  = b0 + bl;
    int c0 = blockIdx.x * 8;

    {
        int r1 = t >> 4, m2 = t & 15;
        float sn, cs;
        sincospif((float)(r1 * m2) / 128.0f, &sn, &cs);
        tw256[t] = make_float2(cs, -sn);
    }
    // phase-A twiddles W4096^{t*k1} (channel-invariant)
    float2 twA[15];
    #pragma unroll
    for (int k1 = 1; k1 < 16; ++k1) {
        float sn, cs;
        sincospif((float)(t * k1) / 2048.0f, &sn, &cs);
        twA[k1 - 1] = make_float2(cs, -sn);
    }
    float accx[16], accy[16];
    #pragma unroll
    for (int r = 0; r < 16; ++r) { accx[r] = 0.f; accy[r] = 0.f; }
    __syncthreads();

    const int rowB = t >> 4, m2B = t & 15;
    const int k1C = t & 15, r1C = t >> 4;

    for (int cc = 0; cc < 8; ++cc) {
        const float2* zc = z + ((size_t)bl * C_ + (c0 + cc)) * L_;
        float2 a[16];
        // ---- phase A ----
        #pragma unroll
        for (int n1 = 0; n1 < 16; ++n1) a[n1] = zc[(n1 << 8) + t];
        fft16(a);
        #pragma unroll
        for (int k1 = 0; k1 < 16; ++k1) {
            float2 v = a[br4[k1]];
            if (k1) v = cmul(v, twA[k1 - 1]);
            s[k1 * RPAD + t] = v;
        }
        __syncthreads();
        // ---- phase B ----
        #pragma unroll
        for (int m1 = 0; m1 < 16; ++m1) a[m1] = s[rowB * RPAD + (m1 << 4) + m2B];
        fft16(a);
        __syncthreads();
        #pragma unroll
        for (int r1 = 0; r1 < 16; ++r1) {
            float2 v = cmul(a[br4[r1]], tw256[(r1 << 4) + m2B]);
            s[rowB * RPAD + (r1 << 4) + m2B] = v;
        }
        __syncthreads();
        // ---- phase C ----
        #pragma unroll
        for (int m2 = 0; m2 < 16; ++m2) a[m2] = s[k1C * RPAD + (r1C << 4) + m2];
        fft16(a);
        __syncthreads();
        #pragma unroll
        for (int r2 = 0; r2 < 16; ++r2)
            s[(r2 << 8) + (r1C << 4) + k1C] = a[br4[r2]];   // natural order, flat
        __syncthreads();
        // ---- unpack Z=Q+iK, accumulate Q*conj(K) (natural bin order) ----
        #pragma unroll
        for (int r = 0; r < 16; ++r) {
            int p  = t + (r << 8);
            int pp = (L_ - p) & (L_ - 1);
            float2 A  = s[p];
            float2 Bv = s[pp];
            float Qr = 0.5f * (A.x + Bv.x);
            float Qi = 0.5f * (A.y - Bv.y);
            float Kr = 0.5f * (A.y + Bv.y);
            float Ki = 0.5f * (A.x - Bv.x);
            accx[r] += Qr * Kr - Qi * Ki;
            accy[r] += Qr * Ki + Qi * Kr;
        }
        __syncthreads();
    }
    #pragma unroll
    for (int r = 0; r < 16; ++r) {
        int p = t + (r << 8);
        atomicAdd(&cross[((size_t)b * L_ + p) * 2 + 0], accx[r]);
        atomicAdd(&cross[((size_t)b * L_ + p) * 2 + 1], accy[r]);
    }
}

// ---------------- inverse DIT FFT (natural-order cross input via bit-rev gather) ----------------
__global__ __launch_bounds__(256) void k_ifft(const float* __restrict__ cross,
                                              float* __restrict__ mv) {
    __shared__ float2 s[L_];
    __shared__ float2 tw[L_ / 2];
    int tid = threadIdx.x;
    int b   = blockIdx.x;
    for (int j = tid; j < L_ / 2; j += NT) {
        float sn, cs;
        sincospif((float)j / 2048.0f, &sn, &cs);
        tw[j] = make_float2(cs, -sn);
    }
    const float2* cr = (const float2*)cross;
    #pragma unroll
    for (int r = 0; r < 16; ++r) {
        int p = tid + (r << 8);
        s[p] = cr[(size_t)b * L_ + br12(p)];
    }
    __syncthreads();
    for (int m = 1; m <= 12; ++m) {
        int half = 1 << (m - 1);
        #pragma unroll
        for (int t8 = 0; t8 < 8; ++t8) {
            int t  = tid + (t8 << 8);
            int kk = t & (half - 1);
            int i0 = ((t >> (m - 1)) << m) | kk;
            int i1 = i0 + half;
            float2 a = s[i0], bb = s[i1];
            float2 w = tw[kk << (12 - m)];
            float bwx = bb.x * w.x + bb.y * w.y;   // b * conj(w)
            float bwy = bb.y * w.x - bb.x * w.y;
            s[i0] = make_float2(a.x + bwx, a.y + bwy);
            s[i1] = make_float2(a.x - bwx, a.y - bwy);
        }
        __syncthreads();
    }
    const float scale = 1.0f / ((float)L_ * (float)C_);
    #pragma unroll
    for (int r = 0; r < 16; ++r) {
        int p = tid + (r << 8);
        mv[(size_t)b * L_ + p] = s[p].x * scale;
    }
}

// ---------------- top-24 + per-batch softmax ----------------
__global__ __launch_bounds__(256) void k_topk(const float* __restrict__ mv,
                                              int* __restrict__ idx,
                                              float* __restrict__ wts) {
    __shared__ float sc[L_];
    __shared__ float rv[NT];
    __shared__ int   ri[NT];
    __shared__ int   idxL[K_];
    int tid = threadIdx.x;
    for (int r = 0; r < 16; ++r) {
        int t = tid + (r << 8);
        float ssum = 0.f;
        for (int b = 0; b < B_; ++b) ssum += mv[(size_t)b * L_ + t];
        sc[t] = ssum;
    }
    __syncthreads();
    for (int i = 0; i < K_; ++i) {
        float best = -INFINITY; int bi = L_;
        for (int r = 0; r < 16; ++r) {
            int t = tid + (r << 8);
            float v = sc[t];
            if (v > best || (v == best && t < bi)) { best = v; bi = t; }
        }
        rv[tid] = best; ri[tid] = bi;
        __syncthreads();
        for (int off = 128; off > 0; off >>= 1) {
            if (tid < off) {
                float v2 = rv[tid + off]; int i2 = ri[tid + off];
                if (v2 > rv[tid] || (v2 == rv[tid] && i2 < ri[tid])) { rv[tid] = v2; ri[tid] = i2; }
            }
            __syncthreads();
        }
        if (tid == 0) { idxL[i] = ri[0]; idx[i] = ri[0]; sc[ri[0]] = -INFINITY; }
        __syncthreads();
    }
    if (tid < B_) {
        int b = tid;
        float w[K_]; float wm = -INFINITY;
        for (int i = 0; i < K_; ++i) { w[i] = mv[(size_t)b * L_ + idxL[i]]; wm = fmaxf(wm, w[i]); }
        float ssum = 0.f;
        for (int i = 0; i < K_; ++i) { w[i] = expf(w[i] - wm); ssum += w[i]; }
        float inv = 1.f / ssum;
        for (int i = 0; i < K_; ++i) wts[b * K_ + i] = w[i] * inv;
    }
}

// ---------------- 24-tap circulant gather-sum, LDS tau-ring version ----------------
// block = (batch b, channel-quad c0..c0+3, ALL 4096 taus).
// Stage V[b, :, c0:c0+4] (4096 x 16B = 64 KB) into LDS once -> V read exactly
// once from global; the 24x tap reuse is served from LDS (ds_read_b128,
// contiguous per wave -> conflict-free).
// Per-tau 16B global slices are 2KB-strided; the 8 blocks sharing each 128B
// line (channel-quads 8k..8k+7) are mapped to the SAME XCD (id%8 = XCD, each
// XCD owns 2 whole batches) so per-XCD L2 dedups both read fills and
// partial-line write merges among co-resident sharers.
__global__ __launch_bounds__(256) void k_agg(const float* __restrict__ vals,
                                             const int* __restrict__ idx,
                                             const float* __restrict__ wts,
                                             float* __restrict__ out) {
    __shared__ float4 sv[L_];      // 64 KB ring: 2 blocks/CU
    __shared__ int   di[K_];
    __shared__ float dw[K_];
    const int tid = threadIdx.x;
    // XCD-aware bijective decode: 2048 blocks; xcd = id&7 owns work [xcd*256, xcd*256+256)
    int id = blockIdx.x;
    int wk = ((id & 7) << 8) | (id >> 3);
    int b  = wk >> 7;              // 0..15 (2 batches per XCD)
    int c0 = (wk & 127) << 2;      // channel-quad start

    if (tid < K_) { di[tid] = idx[tid]; dw[tid] = wts[b * K_ + tid]; }

    // ---- stage: 16 iters x 256 lanes x 16B, LDS dest linear (wave-uniform base + lane*16)
    const float* gbase = vals + (size_t)b * L_ * C_ + c0;
    #pragma unroll
    for (int it = 0; it < 16; ++it) {
        int tau = (it << 8) + tid;
        const float* g = gbase + (size_t)tau * C_;
        float4* l = &sv[(it << 8) + ((tid >> 6) << 6)];   // wave-uniform within each wave
        __builtin_amdgcn_global_load_lds(
            (const __attribute__((address_space(1))) uint32_t*)g,
            (__attribute__((address_space(3))) uint32_t*)l,
            16, 0, 0);
    }
    __syncthreads();   // drains vmcnt before barrier

    // taps/weights to registers (fully-unrolled static indexing)
    int   dir[K_]; float dwr[K_];
    #pragma unroll
    for (int i = 0; i < K_; ++i) { dir[i] = di[i]; dwr[i] = dw[i]; }

    float* obase = out + (size_t)b * L_ * C_ + c0;
    for (int r = 0; r < 16; ++r) {
        int tau = (r << 8) + tid;
        float4 acc = make_float4(0.f, 0.f, 0.f, 0.f);
        #pragma unroll
        for (int i = 0; i < K_; ++i) {
            float4 x = sv[(tau + dir[i]) & (L_ - 1)];
            float w = dwr[i];
            acc.x = fmaf(w, x.x, acc.x);
            acc.y = fmaf(w, x.y, acc.y);
            acc.z = fmaf(w, x.z, acc.z);
            acc.w = fmaf(w, x.w, acc.w);
        }
        *(float4*)(obase + (size_t)tau * C_) = acc;
    }
}

extern "C" void kernel_launch(void* const* d_in, const int* in_sizes, int n_in,
                              void* d_out, int out_size, void* d_ws, size_t ws_size,
                              hipStream_t stream) {
    const float* q = (const float*)d_in[0];
    const float* k = (const float*)d_in[1];
    const float* v = (const float*)d_in[2];
    float* out = (float*)d_out;
    char* ws = (char*)d_ws;

    // ws layout: [cross 512KB | mv 256KB | idx | wts | ... | z at 2MB]
    float* cross = (float*)ws;
    float* mv    = (float*)(ws + (1 << 20));
    int*   idx   = (int*)(ws + (1 << 20) + (1 << 18));
    float* wts   = (float*)(ws + (1 << 20) + (1 << 18) + 4096);
    float2* z    = (float2*)(ws + (2 << 20));

    size_t zcap = (ws_size > (size_t)(2 << 20)) ? ws_size - (size_t)(2 << 20) : 0;
    int P = 16;
    while (P > 1 && (size_t)P * C_ * L_ * sizeof(float2) > zcap) P >>= 1;

    k_zero<<<(B_ * L_ * 2 + 255) / 256, 256, 0, stream>>>(cross, B_ * L_ * 2);

    for (int b0 = 0; b0 < B_; b0 += P) {
        dim3 gt(L_ / 64, C_ / 64, P);
        k_transpose<<<gt, 256, 0, stream>>>(q, k, z, b0);
        dim3 gf(C_ / 8, P);
        k_fft_accum<<<gf, 256, 0, stream>>>(z, cross, b0);
    }
    k_ifft<<<B_, 256, 0, stream>>>(cross, mv);
    k_topk<<<1, 256, 0, stream>>>(mv, idx, wts);
    k_agg<<<B_ * (C_ / 4) / 8 * 8, 256, 0, stream>>>(v, idx, wts, out);
}

// Round 2
// 379.617 us; speedup vs baseline: 1.3664x; 1.0377x over previous
//
#include <hip/hip_runtime.h>
#include <math.h>

#define B_ 16
#define L_ 4096
#define H_ 8
#define E_ 64
#define C_ 512     // H*E
#define K_ 24
#define NT 256
#define RPAD 257   // padded row stride (float2 units) for the 16x256 LDS matrix

__device__ __forceinline__ int br12(int x) { return (int)(__brev((unsigned)x) >> 20); }

__device__ __forceinline__ float2 cmul(float2 a, float2 b) {
    return make_float2(a.x * b.x - a.y * b.y, a.x * b.y + a.y * b.x);
}
__device__ __forceinline__ float2 cadd(float2 a, float2 b) { return make_float2(a.x + b.x, a.y + b.y); }
__device__ __forceinline__ float2 csub(float2 a, float2 b) { return make_float2(a.x - b.x, a.y - b.y); }

// barrier that orders LDS only: does NOT drain vmcnt, so register prefetch
// loads stay in flight across it (no cross-thread global deps at these points)
__device__ __forceinline__ void bar_lds() {
    asm volatile("s_waitcnt lgkmcnt(0)" ::: "memory");
    __builtin_amdgcn_s_barrier();
}

// 16-point DIF FFT, natural-order input; output: X[k] = a[br4[k]]
__device__ __forceinline__ void fft16(float2 a[16]) {
    const float r2 = 0.70710678118654752f;
    const float c1 = 0.92387953251128676f;  // cos(pi/8)
    const float s1 = 0.38268343236508977f;  // sin(pi/8)
    const float2 W16[8] = {
        make_float2(1.f, 0.f),  make_float2(c1, -s1),  make_float2(r2, -r2),  make_float2(s1, -c1),
        make_float2(0.f, -1.f), make_float2(-s1, -c1), make_float2(-r2, -r2), make_float2(-c1, -s1)};
    #pragma unroll
    for (int j = 0; j < 8; ++j) {
        float2 u = a[j], v = a[j + 8];
        a[j]     = cadd(u, v);
        a[j + 8] = cmul(csub(u, v), W16[j]);
    }
    #pragma unroll
    for (int b = 0; b < 16; b += 8)
        #pragma unroll
        for (int j = 0; j < 4; ++j) {
            float2 u = a[b + j], v = a[b + j + 4];
            a[b + j]     = cadd(u, v);
            a[b + j + 4] = cmul(csub(u, v), W16[2 * j]);
        }
    #pragma unroll
    for (int b = 0; b < 16; b += 4)
        #pragma unroll
        for (int j = 0; j < 2; ++j) {
            float2 u = a[b + j], v = a[b + j + 2];
            a[b + j]     = cadd(u, v);
            a[b + j + 2] = cmul(csub(u, v), W16[4 * j]);
        }
    #pragma unroll
    for (int b = 0; b < 16; b += 2) {
        float2 u = a[b], v = a[b + 1];
        a[b]     = cadd(u, v);
        a[b + 1] = csub(u, v);
    }
}

// ---------------- zero scratch ----------------
__global__ __launch_bounds__(256) void k_zero(float* __restrict__ p, int n) {
    int i = blockIdx.x * 256 + threadIdx.x;
    if (i < n) p[i] = 0.f;
}

// ---------------- transpose/pack: (b,tau,c) -> z[bl][c][tau] = (q,k) ----------------
// float4 on both global sides (16 B/lane); LDS staged with [64][65] (2-way = free)
__global__ __launch_bounds__(256) void k_transpose(const float* __restrict__ q,
                                                   const float* __restrict__ k,
                                                   float2* __restrict__ z,
                                                   int b0) {
    __shared__ float tq[64][65];
    __shared__ float tk[64][65];
    int bl = blockIdx.z;
    int b  = b0 + bl;
    int t0 = blockIdx.x * 64;
    int c0 = blockIdx.y * 64;
    int tid  = threadIdx.x;
    int row  = tid >> 4;          // 0..15
    int col4 = (tid & 15) << 2;   // 0,4,..,60
    const size_t base = (size_t)b * L_ * C_;
    #pragma unroll
    for (int p = 0; p < 4; ++p) {
        int rr = (p << 4) + row;   // tau row in tile
        size_t off = base + (size_t)(t0 + rr) * C_ + (c0 + col4);
        float4 q4 = *(const float4*)(q + off);
        float4 k4 = *(const float4*)(k + off);
        tq[rr][col4 + 0] = q4.x; tq[rr][col4 + 1] = q4.y;
        tq[rr][col4 + 2] = q4.z; tq[rr][col4 + 3] = q4.w;
        tk[rr][col4 + 0] = k4.x; tk[rr][col4 + 1] = k4.y;
        tk[rr][col4 + 2] = k4.z; tk[rr][col4 + 3] = k4.w;
    }
    __syncthreads();
    #pragma unroll
    for (int p = 0; p < 4; ++p) {
        int cc = (p << 4) + row;   // channel row in tile
        int tg = col4;             // tau group of 4
        float4 w0 = make_float4(tq[tg + 0][cc], tk[tg + 0][cc],
                                tq[tg + 1][cc], tk[tg + 1][cc]);
        float4 w1 = make_float4(tq[tg + 2][cc], tk[tg + 2][cc],
                                tq[tg + 3][cc], tk[tg + 3][cc]);
        size_t zoff = ((size_t)bl * C_ + (c0 + cc)) * L_ + (t0 + tg);
        *(float4*)&z[zoff]     = w0;
        *(float4*)&z[zoff + 2] = w1;
    }
}

// ---------------- forward FFT (register radix-16, 3 phases) + cross-spectrum ----------------
// Changes vs prev round:
//  * next channel's z prefetched into a[16] (dead during accum) -> zero extra VGPR,
//    loads in flight across 2 LDS-only barriers + accum phase
//  * removed redundant barrier inside phase B (each thread's read set == write set:
//    cells {rowB*RPAD + j*16 + m2B} are thread-exclusive)
__global__ __launch_bounds__(256) void k_fft_accum(const float2* __restrict__ z,
                                                   float* __restrict__ cross, // B*L*2 floats
                                                   int b0) {
    __shared__ float2 s[16 * RPAD];   // 4112 float2 = 32.9 KB
    __shared__ float2 tw256[256];     // tw256[r1*16+m2] = W256^{m2*r1}
    const int br4[16] = {0, 8, 4, 12, 2, 10, 6, 14, 1, 9, 5, 13, 3, 11, 7, 15};
    int t  = threadIdx.x;
    int bl = blockIdx.y;
    int b  = b0 + bl;
    int c0 = blockIdx.x * 8;

    {
        int r1 = t >> 4, m2 = t & 15;
        float sn, cs;
        sincospif((float)(r1 * m2) / 128.0f, &sn, &cs);
        tw256[t] = make_float2(cs, -sn);
    }
    // phase-A twiddles W4096^{t*k1} (channel-invariant)
    float2 twA[15];
    #pragma unroll
    for (int k1 = 1; k1 < 16; ++k1) {
        float sn, cs;
        sincospif((float)(t * k1) / 2048.0f, &sn, &cs);
        twA[k1 - 1] = make_float2(cs, -sn);
    }
    float accx[16], accy[16];
    #pragma unroll
    for (int r = 0; r < 16; ++r) { accx[r] = 0.f; accy[r] = 0.f; }

    // preload channel 0 (in flight across the tw-setup barrier)
    float2 a[16];
    {
        const float2* zc0 = z + ((size_t)bl * C_ + c0) * L_;
        #pragma unroll
        for (int j = 0; j < 16; ++j) a[j] = zc0[(j << 8) + t];
    }
    bar_lds();   // tw256 ready; prefetch stays outstanding

    const int rowB = t >> 4, m2B = t & 15;
    const int k1C = t & 15, r1C = t >> 4;

    for (int cc = 0; cc < 8; ++cc) {
        // ---- phase A (a[] preloaded) ----
        fft16(a);
        #pragma unroll
        for (int k1 = 0; k1 < 16; ++k1) {
            float2 v = a[br4[k1]];
            if (k1) v = cmul(v, twA[k1 - 1]);
            s[k1 * RPAD + t] = v;
        }
        __syncthreads();
        // ---- phase B (no mid barrier: cells thread-exclusive) ----
        #pragma unroll
        for (int m1 = 0; m1 < 16; ++m1) a[m1] = s[rowB * RPAD + (m1 << 4) + m2B];
        fft16(a);
        #pragma unroll
        for (int r1 = 0; r1 < 16; ++r1) {
            float2 v = cmul(a[br4[r1]], tw256[(r1 << 4) + m2B]);
            s[rowB * RPAD + (r1 << 4) + m2B] = v;
        }
        __syncthreads();
        // ---- phase C ----
        #pragma unroll
        for (int m2 = 0; m2 < 16; ++m2) a[m2] = s[k1C * RPAD + (r1C << 4) + m2];
        fft16(a);
        __syncthreads();
        #pragma unroll
        for (int r2 = 0; r2 < 16; ++r2)
            s[(r2 << 8) + (r1C << 4) + k1C] = a[br4[r2]];   // natural order, flat
        // ---- prefetch next channel into now-dead a[] ----
        if (cc < 7) {
            const float2* zn = z + ((size_t)bl * C_ + (c0 + cc + 1)) * L_;
            #pragma unroll
            for (int j = 0; j < 16; ++j) a[j] = zn[(j << 8) + t];
        }
        bar_lds();   // LDS-ordering only; prefetch stays in flight
        // ---- unpack Z=Q+iK, accumulate Q*conj(K) (natural bin order) ----
        #pragma unroll
        for (int r = 0; r < 16; ++r) {
            int p  = t + (r << 8);
            int pp = (L_ - p) & (L_ - 1);
            float2 A  = s[p];
            float2 Bv = s[pp];
            float Qr = 0.5f * (A.x + Bv.x);
            float Qi = 0.5f * (A.y - Bv.y);
            float Kr = 0.5f * (A.y + Bv.y);
            float Ki = 0.5f * (A.x - Bv.x);
            accx[r] += Qr * Kr - Qi * Ki;
            accy[r] += Qr * Ki + Qi * Kr;
        }
        bar_lds();   // accum reads done before next phase A overwrites s
    }
    #pragma unroll
    for (int r = 0; r < 16; ++r) {
        int p = t + (r << 8);
        atomicAdd(&cross[((size_t)b * L_ + p) * 2 + 0], accx[r]);
        atomicAdd(&cross[((size_t)b * L_ + p) * 2 + 1], accy[r]);
    }
}

// ---------------- inverse DIT FFT (natural-order cross input via bit-rev gather) ----------------
__global__ __launch_bounds__(256) void k_ifft(const float* __restrict__ cross,
                                              float* __restrict__ mv) {
    __shared__ float2 s[L_];
    __shared__ float2 tw[L_ / 2];
    int tid = threadIdx.x;
    int b   = blockIdx.x;
    for (int j = tid; j < L_ / 2; j += NT) {
        float sn, cs;
        sincospif((float)j / 2048.0f, &sn, &cs);
        tw[j] = make_float2(cs, -sn);
    }
    const float2* cr = (const float2*)cross;
    #pragma unroll
    for (int r = 0; r < 16; ++r) {
        int p = tid + (r << 8);
        s[p] = cr[(size_t)b * L_ + br12(p)];
    }
    __syncthreads();
    for (int m = 1; m <= 12; ++m) {
        int half = 1 << (m - 1);
        #pragma unroll
        for (int t8 = 0; t8 < 8; ++t8) {
            int t  = tid + (t8 << 8);
            int kk = t & (half - 1);
            int i0 = ((t >> (m - 1)) << m) | kk;
            int i1 = i0 + half;
            float2 a = s[i0], bb = s[i1];
            float2 w = tw[kk << (12 - m)];
            float bwx = bb.x * w.x + bb.y * w.y;   // b * conj(w)
            float bwy = bb.y * w.x - bb.x * w.y;
            s[i0] = make_float2(a.x + bwx, a.y + bwy);
            s[i1] = make_float2(a.x - bwx, a.y - bwy);
        }
        __syncthreads();
    }
    const float scale = 1.0f / ((float)L_ * (float)C_);
    #pragma unroll
    for (int r = 0; r < 16; ++r) {
        int p = tid + (r << 8);
        mv[(size_t)b * L_ + p] = s[p].x * scale;
    }
}

// ---------------- top-24 + per-batch softmax (register-resident, wave-shuffle) ----------------
__global__ __launch_bounds__(256) void k_topk(const float* __restrict__ mv,
                                              int* __restrict__ idx,
                                              float* __restrict__ wts) {
    __shared__ float wv[4];
    __shared__ int   wi[4];
    __shared__ int   idxL[K_];
    int tid = threadIdx.x;
    float vloc[16];
    #pragma unroll
    for (int r = 0; r < 16; ++r) {
        int tt = tid + (r << 8);
        float ssum = 0.f;
        for (int b = 0; b < B_; ++b) ssum += mv[(size_t)b * L_ + tt];
        vloc[r] = ssum;
    }
    int lane = tid & 63, w = tid >> 6;
    for (int i = 0; i < K_; ++i) {
        float best = -INFINITY; int bi = 1 << 30;
        #pragma unroll
        for (int r = 0; r < 16; ++r) {
            float v = vloc[r]; int ii = tid + (r << 8);
            if (v > best || (v == best && ii < bi)) { best = v; bi = ii; }
        }
        #pragma unroll
        for (int off = 32; off > 0; off >>= 1) {
            float ov = __shfl_down(best, off);
            int   oi = __shfl_down(bi, off);
            if (ov > best || (ov == best && oi < bi)) { best = ov; bi = oi; }
        }
        if (lane == 0) { wv[w] = best; wi[w] = bi; }
        __syncthreads();
        if (tid == 0) {
            float bb = wv[0]; int bj = wi[0];
            for (int j = 1; j < 4; ++j)
                if (wv[j] > bb || (wv[j] == bb && wi[j] < bj)) { bb = wv[j]; bj = wi[j]; }
            idxL[i] = bj; idx[i] = bj;
        }
        __syncthreads();
        int win = idxL[i];
        #pragma unroll
        for (int r = 0; r < 16; ++r)
            if (win == tid + (r << 8)) vloc[r] = -INFINITY;
    }
    if (tid < B_) {
        int b = tid;
        float ww[K_]; float wm = -INFINITY;
        for (int i = 0; i < K_; ++i) { ww[i] = mv[(size_t)b * L_ + idxL[i]]; wm = fmaxf(wm, ww[i]); }
        float ssum = 0.f;
        for (int i = 0; i < K_; ++i) { ww[i] = expf(ww[i] - wm); ssum += ww[i]; }
        float inv = 1.f / ssum;
        for (int i = 0; i < K_; ++i) wts[b * K_ + i] = ww[i] * inv;
    }
}

// ---------------- 24-tap circulant gather-sum, LDS tau-ring version ----------------
__global__ __launch_bounds__(256) void k_agg(const float* __restrict__ vals,
                                             const int* __restrict__ idx,
                                             const float* __restrict__ wts,
                                             float* __restrict__ out) {
    __shared__ float4 sv[L_];      // 64 KB ring: 2 blocks/CU
    __shared__ int   di[K_];
    __shared__ float dw[K_];
    const int tid = threadIdx.x;
    // XCD-aware bijective decode: 2048 blocks; xcd = id&7 owns work [xcd*256, xcd*256+256)
    int id = blockIdx.x;
    int wk = ((id & 7) << 8) | (id >> 3);
    int b  = wk >> 7;              // 0..15 (2 batches per XCD)
    int c0 = (wk & 127) << 2;      // channel-quad start

    if (tid < K_) { di[tid] = idx[tid]; dw[tid] = wts[b * K_ + tid]; }

    // ---- stage: 16 iters x 256 lanes x 16B, LDS dest linear (wave-uniform base + lane*16)
    const float* gbase = vals + (size_t)b * L_ * C_ + c0;
    #pragma unroll
    for (int it = 0; it < 16; ++it) {
        int tau = (it << 8) + tid;
        const float* g = gbase + (size_t)tau * C_;
        float4* l = &sv[(it << 8) + ((tid >> 6) << 6)];   // wave-uniform within each wave
        __builtin_amdgcn_global_load_lds(
            (const __attribute__((address_space(1))) uint32_t*)g,
            (__attribute__((address_space(3))) uint32_t*)l,
            16, 0, 0);
    }
    __syncthreads();   // drains vmcnt before barrier

    // taps/weights to registers (fully-unrolled static indexing)
    int   dir[K_]; float dwr[K_];
    #pragma unroll
    for (int i = 0; i < K_; ++i) { dir[i] = di[i]; dwr[i] = dw[i]; }

    float* obase = out + (size_t)b * L_ * C_ + c0;
    for (int r = 0; r < 16; ++r) {
        int tau = (r << 8) + tid;
        float4 acc = make_float4(0.f, 0.f, 0.f, 0.f);
        #pragma unroll
        for (int i = 0; i < K_; ++i) {
            float4 x = sv[(tau + dir[i]) & (L_ - 1)];
            float w = dwr[i];
            acc.x = fmaf(w, x.x, acc.x);
            acc.y = fmaf(w, x.y, acc.y);
            acc.z = fmaf(w, x.z, acc.z);
            acc.w = fmaf(w, x.w, acc.w);
        }
        *(float4*)(obase + (size_t)tau * C_) = acc;
    }
}

extern "C" void kernel_launch(void* const* d_in, const int* in_sizes, int n_in,
                              void* d_out, int out_size, void* d_ws, size_t ws_size,
                              hipStream_t stream) {
    const float* q = (const float*)d_in[0];
    const float* k = (const float*)d_in[1];
    const float* v = (const float*)d_in[2];
    float* out = (float*)d_out;
    char* ws = (char*)d_ws;

    // ws layout: [cross 512KB | mv 256KB | idx | wts | ... | z at 2MB]
    float* cross = (float*)ws;
    float* mv    = (float*)(ws + (1 << 20));
    int*   idx   = (int*)(ws + (1 << 20) + (1 << 18));
    float* wts   = (float*)(ws + (1 << 20) + (1 << 18) + 4096);
    float2* z    = (float2*)(ws + (2 << 20));

    size_t zcap = (ws_size > (size_t)(2 << 20)) ? ws_size - (size_t)(2 << 20) : 0;
    int P = 16;
    while (P > 1 && (size_t)P * C_ * L_ * sizeof(float2) > zcap) P >>= 1;

    k_zero<<<(B_ * L_ * 2 + 255) / 256, 256, 0, stream>>>(cross, B_ * L_ * 2);

    for (int b0 = 0; b0 < B_; b0 += P) {
        dim3 gt(L_ / 64, C_ / 64, P);
        k_transpose<<<gt, 256, 0, stream>>>(q, k, z, b0);
        dim3 gf(C_ / 8, P);
        k_fft_accum<<<gf, 256, 0, stream>>>(z, cross, b0);
    }
    k_ifft<<<B_, 256, 0, stream>>>(cross, mv);
    k_topk<<<1, 256, 0, stream>>>(mv, idx, wts);
    k_agg<<<B_ * (C_ / 4) / 8 * 8, 256, 0, stream>>>(v, idx, wts, out);
}

// Round 3
// 361.093 us; speedup vs baseline: 1.4364x; 1.0513x over previous
//
#include <hip/hip_runtime.h>
#include <math.h>

#define B_ 16
#define L_ 4096
#define H_ 8
#define E_ 64
#define C_ 512     // H*E
#define K_ 24
#define NT 256
#define RPAD 257   // padded row stride (float2 units) for the 16x256 LDS matrix

__device__ __forceinline__ float2 cmul(float2 a, float2 b) {
    return make_float2(a.x * b.x - a.y * b.y, a.x * b.y + a.y * b.x);
}
__device__ __forceinline__ float2 cadd(float2 a, float2 b) { return make_float2(a.x + b.x, a.y + b.y); }
__device__ __forceinline__ float2 csub(float2 a, float2 b) { return make_float2(a.x - b.x, a.y - b.y); }

// barrier that orders LDS only: does NOT drain vmcnt, so register prefetch
// loads stay in flight across it (no cross-thread global deps at these points)
__device__ __forceinline__ void bar_lds() {
    asm volatile("s_waitcnt lgkmcnt(0)" ::: "memory");
    __builtin_amdgcn_s_barrier();
}

// 16-point DIF FFT, natural-order input; output: X[k] = a[br4[k]]
__device__ __forceinline__ void fft16(float2 a[16]) {
    const float r2 = 0.70710678118654752f;
    const float c1 = 0.92387953251128676f;  // cos(pi/8)
    const float s1 = 0.38268343236508977f;  // sin(pi/8)
    const float2 W16[8] = {
        make_float2(1.f, 0.f),  make_float2(c1, -s1),  make_float2(r2, -r2),  make_float2(s1, -c1),
        make_float2(0.f, -1.f), make_float2(-s1, -c1), make_float2(-r2, -r2), make_float2(-c1, -s1)};
    #pragma unroll
    for (int j = 0; j < 8; ++j) {
        float2 u = a[j], v = a[j + 8];
        a[j]     = cadd(u, v);
        a[j + 8] = cmul(csub(u, v), W16[j]);
    }
    #pragma unroll
    for (int b = 0; b < 16; b += 8)
        #pragma unroll
        for (int j = 0; j < 4; ++j) {
            float2 u = a[b + j], v = a[b + j + 4];
            a[b + j]     = cadd(u, v);
            a[b + j + 4] = cmul(csub(u, v), W16[2 * j]);
        }
    #pragma unroll
    for (int b = 0; b < 16; b += 4)
        #pragma unroll
        for (int j = 0; j < 2; ++j) {
            float2 u = a[b + j], v = a[b + j + 2];
            a[b + j]     = cadd(u, v);
            a[b + j + 2] = cmul(csub(u, v), W16[4 * j]);
        }
    #pragma unroll
    for (int b = 0; b < 16; b += 2) {
        float2 u = a[b], v = a[b + 1];
        a[b]     = cadd(u, v);
        a[b + 1] = csub(u, v);
    }
}

// ---------------- zero scratch ----------------
__global__ __launch_bounds__(256) void k_zero(float* __restrict__ p, int n) {
    int i = blockIdx.x * 256 + threadIdx.x;
    if (i < n) p[i] = 0.f;
}

// ---------------- fused transpose + FFT phase A (four-step split) ----------------
// n = n1*256 + n2.  Block = (n2 window of 16) x (16 channels) x batch.
// Loads rows tau = n1*256 + n2 (64B segments; the two 16-ch blocks sharing a
// 128B line have ids differing by 16 == 0 mod 8 -> same XCD -> L2 dedup),
// LDS-transposes, each thread does DFT16 over n1 for its (ch, n2), applies
// W4096^{n2*k1} via recurrence, writes z[c][k1*256+n2] as full 128B lines --
// which is exactly kernel-2's coalesced gather order.
__global__ __launch_bounds__(256) void k_phaseA(const float* __restrict__ q,
                                                const float* __restrict__ k,
                                                float2* __restrict__ z,
                                                int b0) {
    __shared__ float2 s2[256 * 17];   // [row = n1*16 + n2loc][ch], stride 17 -> 34.8 KB
    const int br4[16] = {0, 8, 4, 12, 2, 10, 6, 14, 1, 9, 5, 13, 3, 11, 7, 15};
    int w  = blockIdx.x;              // n2 window (16 of them)
    int g  = blockIdx.y;              // channel group of 16 (32 of them)
    int bl = blockIdx.z;
    int b  = b0 + bl;
    int tid = threadIdx.x;

    // ---- load 256 rows x 16 ch, float4 per (row, quad) ----
    const size_t base = (size_t)b * L_ * C_ + g * 16;
    int lrow = tid >> 2;              // 0..63
    int lq   = tid & 3;               // quad within 16 channels
    #pragma unroll
    for (int it = 0; it < 4; ++it) {
        int r   = lrow + (it << 6);                     // row = n1*16 + n2loc
        int tau = ((r >> 4) << 8) + (w << 4) + (r & 15);
        const float4 q4 = *(const float4*)(q + base + (size_t)tau * C_ + (lq << 2));
        const float4 k4 = *(const float4*)(k + base + (size_t)tau * C_ + (lq << 2));
        float2* dst = &s2[r * 17 + (lq << 2)];
        dst[0] = make_float2(q4.x, k4.x);
        dst[1] = make_float2(q4.y, k4.y);
        dst[2] = make_float2(q4.z, k4.z);
        dst[3] = make_float2(q4.w, k4.w);
    }
    __syncthreads();

    // ---- compute: thread = (ch = tid>>4, n2loc = tid&15) ----
    int ch = tid >> 4, n2loc = tid & 15;
    int n2 = (w << 4) + n2loc;
    float2 a[16];
    int rbase = n2loc * 17 + ch;
    #pragma unroll
    for (int n1 = 0; n1 < 16; ++n1) a[n1] = s2[n1 * 272 + rbase];
    fft16(a);
    // twiddle W4096^{n2*k1} by recurrence (1 sincos + 15 cmul)
    float sn, cs;
    sincospif((float)n2 / 2048.0f, &sn, &cs);
    const float2 w1 = make_float2(cs, -sn);
    float2 tw = w1;
    float2* zc = z + ((size_t)bl * C_ + (g * 16 + ch)) * L_ + n2;
    zc[0] = a[0];                      // k1 = 0 (br4[0]=0, tw=1)
    #pragma unroll
    for (int k1 = 1; k1 < 16; ++k1) {
        zc[(size_t)(k1 << 8)] = cmul(a[br4[k1]], tw);
        tw = cmul(tw, w1);
    }
}

// ---------------- FFT phases B+C + cross-spectrum accumulate ----------------
// z[c][k1*256+n2] holds phase-A output (twiddled). Thread t: rowB = t>>4 = k1,
// m2B = t&15. Phase B: DFT16 over m1 (n2 = m1*16+m2), twiddle W256^{m2*r1}.
// Phase C: DFT16 over m2 -> r2, natural store X[r2*256+r1*16+k1], accumulate
// Q*conj(K). Next channel's z prefetched into dead a[] across 2 LDS barriers.
__global__ __launch_bounds__(256) void k_fft_bc(const float2* __restrict__ z,
                                                float* __restrict__ cross, // B*L*2 floats
                                                int b0) {
    __shared__ float2 s[16 * RPAD];
    __shared__ float2 tw256[256];     // tw256[r1*16+m2] = W256^{m2*r1}
    const int br4[16] = {0, 8, 4, 12, 2, 10, 6, 14, 1, 9, 5, 13, 3, 11, 7, 15};
    int t  = threadIdx.x;
    int bl = blockIdx.y;
    int b  = b0 + bl;
    int c0 = blockIdx.x * 8;

    {
        int r1 = t >> 4, m2 = t & 15;
        float sn, cs;
        sincospif((float)(r1 * m2) / 128.0f, &sn, &cs);
        tw256[t] = make_float2(cs, -sn);
    }
    float accx[16], accy[16];
    #pragma unroll
    for (int r = 0; r < 16; ++r) { accx[r] = 0.f; accy[r] = 0.f; }

    const int rowB = t >> 4, m2B = t & 15;
    const int k1C = t & 15, r1C = t >> 4;

    // prefetch channel 0 (stays in flight across the setup barrier)
    float2 a[16];
    {
        const float2* zc0 = z + ((size_t)bl * C_ + c0) * L_;
        #pragma unroll
        for (int m1 = 0; m1 < 16; ++m1) a[m1] = zc0[(rowB << 8) + (m1 << 4) + m2B];
    }
    bar_lds();   // tw256 ready

    for (int cc = 0; cc < 8; ++cc) {
        // ---- phase B (input prefetched in a[]) ----
        fft16(a);
        #pragma unroll
        for (int r1 = 0; r1 < 16; ++r1)
            s[rowB * RPAD + (r1 << 4) + m2B] = cmul(a[br4[r1]], tw256[(r1 << 4) + m2B]);
        __syncthreads();
        // ---- phase C ----
        #pragma unroll
        for (int m2 = 0; m2 < 16; ++m2) a[m2] = s[k1C * RPAD + (r1C << 4) + m2];
        fft16(a);
        __syncthreads();
        #pragma unroll
        for (int r2 = 0; r2 < 16; ++r2)
            s[(r2 << 8) + (r1C << 4) + k1C] = a[br4[r2]];   // natural order, flat
        // ---- prefetch next channel into now-dead a[] ----
        if (cc < 7) {
            const float2* zn = z + ((size_t)bl * C_ + (c0 + cc + 1)) * L_;
            #pragma unroll
            for (int m1 = 0; m1 < 16; ++m1) a[m1] = zn[(rowB << 8) + (m1 << 4) + m2B];
        }
        bar_lds();   // LDS-ordering only; prefetch stays in flight
        // ---- unpack Z=Q+iK, accumulate Q*conj(K) (natural bin order) ----
        #pragma unroll
        for (int r = 0; r < 16; ++r) {
            int p  = t + (r << 8);
            int pp = (L_ - p) & (L_ - 1);
            float2 A  = s[p];
            float2 Bv = s[pp];
            float Qr = 0.5f * (A.x + Bv.x);
            float Qi = 0.5f * (A.y - Bv.y);
            float Kr = 0.5f * (A.y + Bv.y);
            float Ki = 0.5f * (A.x - Bv.x);
            accx[r] += Qr * Kr - Qi * Ki;
            accy[r] += Qr * Ki + Qi * Kr;
        }
        bar_lds();   // accum reads done before next phase B overwrites s
    }
    #pragma unroll
    for (int r = 0; r < 16; ++r) {
        int p = t + (r << 8);
        atomicAdd(&cross[((size_t)b * L_ + p) * 2 + 0], accx[r]);
        atomicAdd(&cross[((size_t)b * L_ + p) * 2 + 1], accy[r]);
    }
}

// ---------------- inverse FFT via conj-forward 3-phase radix-16 ----------------
// ifft(X) = conj(FFT(conj(X)))/N; only the real part is needed (Re(conj)=Re).
// Natural-order in (global), natural-order out: phase C writes mv directly,
// coalesced (k = r2*256 + t). 2 barriers total (was 12).
__global__ __launch_bounds__(256) void k_ifft(const float* __restrict__ cross,
                                              float* __restrict__ mv) {
    __shared__ float2 s[16 * RPAD];
    __shared__ float2 tw256[256];
    const int br4[16] = {0, 8, 4, 12, 2, 10, 6, 14, 1, 9, 5, 13, 3, 11, 7, 15};
    int t = threadIdx.x;
    int b = blockIdx.x;
    {
        int r1 = t >> 4, m2 = t & 15;
        float sn, cs;
        sincospif((float)(r1 * m2) / 128.0f, &sn, &cs);
        tw256[t] = make_float2(cs, -sn);
    }
    const float2* cr = (const float2*)cross + (size_t)b * L_;
    float2 a[16];
    #pragma unroll
    for (int n1 = 0; n1 < 16; ++n1) {
        float2 v = cr[(n1 << 8) + t];
        a[n1] = make_float2(v.x, -v.y);          // conj
    }
    // ---- phase A ----
    fft16(a);
    {
        float sn, cs;
        sincospif((float)t / 2048.0f, &sn, &cs);
        const float2 w1 = make_float2(cs, -sn);
        float2 tw = w1;
        s[t] = a[0];
        #pragma unroll
        for (int k1 = 1; k1 < 16; ++k1) {
            s[k1 * RPAD + t] = cmul(a[br4[k1]], tw);
            tw = cmul(tw, w1);
        }
    }
    __syncthreads();
    // ---- phase B (read set == write set: thread-exclusive cells) ----
    const int rowB = t >> 4, m2B = t & 15;
    #pragma unroll
    for (int m1 = 0; m1 < 16; ++m1) a[m1] = s[rowB * RPAD + (m1 << 4) + m2B];
    fft16(a);
    #pragma unroll
    for (int r1 = 0; r1 < 16; ++r1)
        s[rowB * RPAD + (r1 << 4) + m2B] = cmul(a[br4[r1]], tw256[(r1 << 4) + m2B]);
    __syncthreads();
    // ---- phase C: DFT over m2, write mv directly (k = r2*256 + t, coalesced) ----
    const int k1C = t & 15, r1C = t >> 4;
    #pragma unroll
    for (int m2 = 0; m2 < 16; ++m2) a[m2] = s[k1C * RPAD + (r1C << 4) + m2];
    fft16(a);
    const float scale = 1.0f / ((float)L_ * (float)C_);
    #pragma unroll
    for (int r2 = 0; r2 < 16; ++r2)
        mv[(size_t)b * L_ + (r2 << 8) + t] = a[br4[r2]].x * scale;
}

// ---------------- top-24 + per-batch softmax (register-resident, wave-shuffle) ----------------
__global__ __launch_bounds__(256) void k_topk(const float* __restrict__ mv,
                                              int* __restrict__ idx,
                                              float* __restrict__ wts) {
    __shared__ float wv[4];
    __shared__ int   wi[4];
    __shared__ int   idxL[K_];
    int tid = threadIdx.x;
    float vloc[16];
    #pragma unroll
    for (int r = 0; r < 16; ++r) {
        int tt = tid + (r << 8);
        float ssum = 0.f;
        for (int b = 0; b < B_; ++b) ssum += mv[(size_t)b * L_ + tt];
        vloc[r] = ssum;
    }
    int lane = tid & 63, w = tid >> 6;
    for (int i = 0; i < K_; ++i) {
        float best = -INFINITY; int bi = 1 << 30;
        #pragma unroll
        for (int r = 0; r < 16; ++r) {
            float v = vloc[r]; int ii = tid + (r << 8);
            if (v > best || (v == best && ii < bi)) { best = v; bi = ii; }
        }
        #pragma unroll
        for (int off = 32; off > 0; off >>= 1) {
            float ov = __shfl_down(best, off);
            int   oi = __shfl_down(bi, off);
            if (ov > best || (ov == best && oi < bi)) { best = ov; bi = oi; }
        }
        if (lane == 0) { wv[w] = best; wi[w] = bi; }
        __syncthreads();
        if (tid == 0) {
            float bb = wv[0]; int bj = wi[0];
            for (int j = 1; j < 4; ++j)
                if (wv[j] > bb || (wv[j] == bb && wi[j] < bj)) { bb = wv[j]; bj = wi[j]; }
            idxL[i] = bj; idx[i] = bj;
        }
        __syncthreads();
        int win = idxL[i];
        #pragma unroll
        for (int r = 0; r < 16; ++r)
            if (win == tid + (r << 8)) vloc[r] = -INFINITY;
    }
    if (tid < B_) {
        int b = tid;
        float ww[K_]; float wm = -INFINITY;
        for (int i = 0; i < K_; ++i) { ww[i] = mv[(size_t)b * L_ + idxL[i]]; wm = fmaxf(wm, ww[i]); }
        float ssum = 0.f;
        for (int i = 0; i < K_; ++i) { ww[i] = expf(ww[i] - wm); ssum += ww[i]; }
        float inv = 1.f / ssum;
        for (int i = 0; i < K_; ++i) wts[b * K_ + i] = ww[i] * inv;
    }
}

// ---------------- 24-tap circulant gather-sum, LDS tau-ring version ----------------
__global__ __launch_bounds__(256) void k_agg(const float* __restrict__ vals,
                                             const int* __restrict__ idx,
                                             const float* __restrict__ wts,
                                             float* __restrict__ out) {
    __shared__ float4 sv[L_];      // 64 KB ring: 2 blocks/CU
    __shared__ int   di[K_];
    __shared__ float dw[K_];
    const int tid = threadIdx.x;
    // XCD-aware bijective decode: 2048 blocks; xcd = id&7 owns work [xcd*256, xcd*256+256)
    int id = blockIdx.x;
    int wk = ((id & 7) << 8) | (id >> 3);
    int b  = wk >> 7;              // 0..15 (2 batches per XCD)
    int c0 = (wk & 127) << 2;      // channel-quad start

    if (tid < K_) { di[tid] = idx[tid]; dw[tid] = wts[b * K_ + tid]; }

    // ---- stage: 16 iters x 256 lanes x 16B, LDS dest linear (wave-uniform base + lane*16)
    const float* gbase = vals + (size_t)b * L_ * C_ + c0;
    #pragma unroll
    for (int it = 0; it < 16; ++it) {
        int tau = (it << 8) + tid;
        const float* g = gbase + (size_t)tau * C_;
        float4* l = &sv[(it << 8) + ((tid >> 6) << 6)];   // wave-uniform within each wave
        __builtin_amdgcn_global_load_lds(
            (const __attribute__((address_space(1))) uint32_t*)g,
            (__attribute__((address_space(3))) uint32_t*)l,
            16, 0, 0);
    }
    __syncthreads();   // drains vmcnt before barrier

    // taps/weights to registers (fully-unrolled static indexing)
    int   dir[K_]; float dwr[K_];
    #pragma unroll
    for (int i = 0; i < K_; ++i) { dir[i] = di[i]; dwr[i] = dw[i]; }

    float* obase = out + (size_t)b * L_ * C_ + c0;
    for (int r = 0; r < 16; ++r) {
        int tau = (r << 8) + tid;
        float4 acc = make_float4(0.f, 0.f, 0.f, 0.f);
        #pragma unroll
        for (int i = 0; i < K_; ++i) {
            float4 x = sv[(tau + dir[i]) & (L_ - 1)];
            float w = dwr[i];
            acc.x = fmaf(w, x.x, acc.x);
            acc.y = fmaf(w, x.y, acc.y);
            acc.z = fmaf(w, x.z, acc.z);
            acc.w = fmaf(w, x.w, acc.w);
        }
        *(float4*)(obase + (size_t)tau * C_) = acc;
    }
}

extern "C" void kernel_launch(void* const* d_in, const int* in_sizes, int n_in,
                              void* d_out, int out_size, void* d_ws, size_t ws_size,
                              hipStream_t stream) {
    const float* q = (const float*)d_in[0];
    const float* k = (const float*)d_in[1];
    const float* v = (const float*)d_in[2];
    float* out = (float*)d_out;
    char* ws = (char*)d_ws;

    // ws layout: [cross 512KB | mv 256KB | idx | wts | ... | z at 2MB]
    float* cross = (float*)ws;
    float* mv    = (float*)(ws + (1 << 20));
    int*   idx   = (int*)(ws + (1 << 20) + (1 << 18));
    float* wts   = (float*)(ws + (1 << 20) + (1 << 18) + 4096);
    float2* z    = (float2*)(ws + (2 << 20));

    size_t zcap = (ws_size > (size_t)(2 << 20)) ? ws_size - (size_t)(2 << 20) : 0;
    int P = 16;
    while (P > 1 && (size_t)P * C_ * L_ * sizeof(float2) > zcap) P >>= 1;

    k_zero<<<(B_ * L_ * 2 + 255) / 256, 256, 0, stream>>>(cross, B_ * L_ * 2);

    for (int b0 = 0; b0 < B_; b0 += P) {
        dim3 g1(16, 32, P);   // n2 windows x ch groups x batches
        k_phaseA<<<g1, 256, 0, stream>>>(q, k, z, b0);
        dim3 g2(C_ / 8, P);
        k_fft_bc<<<g2, 256, 0, stream>>>(z, cross, b0);
    }
    k_ifft<<<B_, 256, 0, stream>>>(cross, mv);
    k_topk<<<1, 256, 0, stream>>>(mv, idx, wts);
    k_agg<<<B_ * (C_ / 4) / 8 * 8, 256, 0, stream>>>(v, idx, wts, out);
}